// Round 1
// baseline (178.421 us; speedup 1.0000x reference)
//
#include <hip/hip_runtime.h>

#define N_NODES 100000
#define N_EDGES 640000
#define HIDDEN  128
#define EPS     1e-6f

// ---------------------------------------------------------------------------
// Kernel 0: u[k] = sum_j att_w[j]*W[j,k];  v[k] = sum_j att_w[128+j]*W[j,k];
//           c = sum_j att_w[j]*b[j] + att_w[128+j]*b[j]
// One block of 128 threads. W reads are coalesced across k for each j.
// ---------------------------------------------------------------------------
__global__ void precompute_uvc(const float* __restrict__ W,
                               const float* __restrict__ b,
                               const float* __restrict__ att_w,
                               float* __restrict__ u,
                               float* __restrict__ v,
                               float* __restrict__ c) {
    int k = threadIdx.x;  // 0..127
    float su = 0.f, sv = 0.f;
    for (int j = 0; j < HIDDEN; ++j) {
        float w = W[j * HIDDEN + k];
        su += att_w[j] * w;
        sv += att_w[HIDDEN + j] * w;
    }
    u[k] = su;
    v[k] = sv;
    if (k == 0) {
        float cc = 0.f;
        for (int j = 0; j < HIDDEN; ++j)
            cc += att_w[j] * b[j] + att_w[HIDDEN + j] * b[j];
        *c = cc;
    }
}

// ---------------------------------------------------------------------------
// Kernel 1: per-node dots p_i = u.x_i, q_i = v.x_i.
// One wave (64 lanes) per node; lane l loads x[i][2l:2l+2] (512B/row coalesced).
// ---------------------------------------------------------------------------
__global__ void node_dots(const float* __restrict__ x,
                          const float* __restrict__ u,
                          const float* __restrict__ v,
                          float* __restrict__ p,
                          float* __restrict__ q) {
    int node = (int)((blockIdx.x * (unsigned)blockDim.x + threadIdx.x) >> 6);
    int lane = threadIdx.x & 63;
    if (node >= N_NODES) return;

    float2 xv = ((const float2*)(x + (size_t)node * HIDDEN))[lane];
    float2 uv = ((const float2*)u)[lane];
    float2 vv = ((const float2*)v)[lane];

    float sp = xv.x * uv.x + xv.y * uv.y;
    float sq = xv.x * vv.x + xv.y * vv.y;
    #pragma unroll
    for (int off = 32; off > 0; off >>= 1) {
        sp += __shfl_down(sp, off);
        sq += __shfl_down(sq, off);
    }
    if (lane == 0) { p[node] = sp; q[node] = sq; }
}

// ---------------------------------------------------------------------------
// Kernel 2: per-edge a_e = exp(leaky_relu(p[src]+q[dst]+c)), atomic into n[dst].
// p/q/n are 400KB each -> L2/L3 resident; gathers are cheap.
// ---------------------------------------------------------------------------
__global__ void edge_kernel(const int* __restrict__ e,
                            const float* __restrict__ p,
                            const float* __restrict__ q,
                            const float* __restrict__ c,
                            float* __restrict__ n) {
    int eid = blockIdx.x * blockDim.x + threadIdx.x;
    if (eid >= N_EDGES) return;
    int src = e[2 * eid];
    int dst = e[2 * eid + 1];
    float score = p[src] + q[dst] + c[0];
    float lr = score > 0.f ? score : 0.2f * score;
    atomicAdd(&n[dst], expf(lr));
}

// ---------------------------------------------------------------------------
// Kernel 3: y = relu(x / n') + x ; out = norm_w * y * rsqrt(mean(y^2)+eps) + norm_b
// One wave per node, float2 per lane, butterfly reduce for sum(y^2).
// ---------------------------------------------------------------------------
__global__ void final_kernel(const float* __restrict__ x,
                             const float* __restrict__ n,
                             const float* __restrict__ norm_w,
                             const float* __restrict__ norm_b,
                             float* __restrict__ out) {
    int node = (int)((blockIdx.x * (unsigned)blockDim.x + threadIdx.x) >> 6);
    int lane = threadIdx.x & 63;
    if (node >= N_NODES) return;

    float nn = n[node];                       // broadcast load (same addr per wave)
    float inv_n = 1.f / (nn == 0.f ? 1.f : nn);

    float2 xv = ((const float2*)(x + (size_t)node * HIDDEN))[lane];
    float hx = xv.x * inv_n; hx = hx > 0.f ? hx : 0.f;
    float hy = xv.y * inv_n; hy = hy > 0.f ? hy : 0.f;
    float yx = hx + xv.x;
    float yy = hy + xv.y;

    float ss = yx * yx + yy * yy;
    #pragma unroll
    for (int off = 32; off > 0; off >>= 1) ss += __shfl_xor(ss, off);
    float inv_rms = rsqrtf(ss * (1.f / HIDDEN) + EPS);

    float2 wv = ((const float2*)norm_w)[lane];
    float2 bv = ((const float2*)norm_b)[lane];
    float2 ov;
    ov.x = wv.x * (yx * inv_rms) + bv.x;
    ov.y = wv.y * (yy * inv_rms) + bv.y;
    ((float2*)(out + (size_t)node * HIDDEN))[lane] = ov;
}

extern "C" void kernel_launch(void* const* d_in, const int* in_sizes, int n_in,
                              void* d_out, int out_size, void* d_ws, size_t ws_size,
                              hipStream_t stream) {
    const float* x      = (const float*)d_in[0];
    const float* W      = (const float*)d_in[1];
    const float* b      = (const float*)d_in[2];
    const float* att_w  = (const float*)d_in[3];
    const float* norm_w = (const float*)d_in[4];
    const float* norm_b = (const float*)d_in[5];
    const int*   e      = (const int*)d_in[6];
    float* out = (float*)d_out;

    // workspace layout (floats): u[128] v[128] c[1] ... p[N] q[N] n[N]
    float* ws = (float*)d_ws;
    float* u = ws;
    float* v = ws + 128;
    float* c = ws + 256;
    float* p = ws + 1024;
    float* q = p + N_NODES;
    float* nacc = q + N_NODES;

    // n accumulator must start at zero (ws is poisoned each launch)
    hipMemsetAsync(nacc, 0, N_NODES * sizeof(float), stream);

    precompute_uvc<<<1, 128, 0, stream>>>(W, b, att_w, u, v, c);

    {   // wave-per-node: 4 waves/block
        int blocks = (N_NODES + 3) / 4;
        node_dots<<<blocks, 256, 0, stream>>>(x, u, v, p, q);
    }
    {
        int blocks = (N_EDGES + 255) / 256;
        edge_kernel<<<blocks, 256, 0, stream>>>(e, p, q, c, nacc);
    }
    {
        int blocks = (N_NODES + 3) / 4;
        final_kernel<<<blocks, 256, 0, stream>>>(x, nacc, norm_w, norm_b, out);
    }
}

// Round 2
// 160.246 us; speedup vs baseline: 1.1134x; 1.1134x over previous
//
#include <hip/hip_runtime.h>

#define N_NODES 100000
#define N_EDGES 640000
#define HIDDEN  128
#define EPS     1e-6f

// ---------------------------------------------------------------------------
// Kernel 0: u[k] = sum_j att_w[j]*W[j,k];  v[k] = sum_j att_w[128+j]*W[j,k];
//           c = att_w[0:128].b + att_w[128:256].b
// 512 threads: 4 j-chunks x 128 columns, LDS tree reduce. c in parallel on
// the first wave (independent of the main loop).
// ---------------------------------------------------------------------------
__global__ void precompute_uvc(const float* __restrict__ W,
                               const float* __restrict__ b,
                               const float* __restrict__ att_w,
                               float* __restrict__ u,
                               float* __restrict__ v,
                               float* __restrict__ c) {
    __shared__ float su_s[4][HIDDEN];
    __shared__ float sv_s[4][HIDDEN];
    int k     = threadIdx.x & 127;
    int chunk = threadIdx.x >> 7;   // 0..3

    float su = 0.f, sv = 0.f;
    #pragma unroll
    for (int jj = 0; jj < 32; ++jj) {
        int j = chunk * 32 + jj;
        float w = W[j * HIDDEN + k];
        su += att_w[j] * w;
        sv += att_w[HIDDEN + j] * w;
    }
    su_s[chunk][k] = su;
    sv_s[chunk][k] = sv;

    // c: first wave only, fully parallel with the loop above (no LDS dep)
    if (threadIdx.x < 64) {
        int t0 = threadIdx.x, t1 = threadIdx.x + 64;
        float t = att_w[t0] * b[t0] + att_w[HIDDEN + t0] * b[t0]
                + att_w[t1] * b[t1] + att_w[HIDDEN + t1] * b[t1];
        #pragma unroll
        for (int off = 32; off > 0; off >>= 1) t += __shfl_xor(t, off);
        if (threadIdx.x == 0) *c = t;
    }

    __syncthreads();
    if (chunk == 0) {
        u[k] = su_s[0][k] + su_s[1][k] + su_s[2][k] + su_s[3][k];
        v[k] = sv_s[0][k] + sv_s[1][k] + sv_s[2][k] + sv_s[3][k];
    }
}

// ---------------------------------------------------------------------------
// Kernel 1: p_i = u.x_i, q_i = v.x_i, and nacc_i = 0.
// float4 per lane; 32 lanes cover one 128-float row -> 2 nodes per wave,
// wave reads 1 KiB contiguous. Reduce within 32-lane halves via shfl_xor.
// ---------------------------------------------------------------------------
__global__ void node_dots(const float* __restrict__ x,
                          const float* __restrict__ u,
                          const float* __restrict__ v,
                          float* __restrict__ p,
                          float* __restrict__ q,
                          float* __restrict__ nacc) {
    int gid  = blockIdx.x * blockDim.x + threadIdx.x;
    int wave = gid >> 6;
    int lane = threadIdx.x & 63;
    int half = lane >> 5;         // 0 or 1
    int sub  = lane & 31;         // element group within row
    int node = wave * 2 + half;
    if (node >= N_NODES) return;

    float4 xv = ((const float4*)(x + (size_t)node * HIDDEN))[sub];
    float4 uv = ((const float4*)u)[sub];
    float4 vv = ((const float4*)v)[sub];

    float sp = xv.x * uv.x + xv.y * uv.y + xv.z * uv.z + xv.w * uv.w;
    float sq = xv.x * vv.x + xv.y * vv.y + xv.z * vv.z + xv.w * vv.w;
    #pragma unroll
    for (int off = 16; off > 0; off >>= 1) {
        sp += __shfl_xor(sp, off);
        sq += __shfl_xor(sq, off);
    }
    if (sub == 0) {
        p[node]    = sp;
        q[node]    = sq;
        nacc[node] = 0.f;        // replaces the separate memset dispatch
    }
}

// ---------------------------------------------------------------------------
// Kernel 2: a_e = exp(leaky_relu(p[src]+q[dst]+c)), atomicAdd into nacc[dst].
// p/q/nacc are 400KB each -> L2/L3 resident.
// ---------------------------------------------------------------------------
__global__ void edge_kernel(const int* __restrict__ e,
                            const float* __restrict__ p,
                            const float* __restrict__ q,
                            const float* __restrict__ c,
                            float* __restrict__ nacc) {
    int eid = blockIdx.x * blockDim.x + threadIdx.x;
    if (eid >= N_EDGES) return;
    int2 ed = ((const int2*)e)[eid];     // (src, dst) as one dwordx2
    float score = p[ed.x] + q[ed.y] + c[0];
    float lr = score > 0.f ? score : 0.2f * score;
    atomicAdd(&nacc[ed.y], __expf(lr) == __expf(lr) ? expf(lr) : expf(lr));
}

// ---------------------------------------------------------------------------
// Kernel 3: y = relu(x/n') + x ; out = norm_w * y * rsqrt(mean(y^2)+eps) + norm_b
// Same 2-nodes-per-wave float4 layout as node_dots.
// ---------------------------------------------------------------------------
__global__ void final_kernel(const float* __restrict__ x,
                             const float* __restrict__ nacc,
                             const float* __restrict__ norm_w,
                             const float* __restrict__ norm_b,
                             float* __restrict__ out) {
    int gid  = blockIdx.x * blockDim.x + threadIdx.x;
    int wave = gid >> 6;
    int lane = threadIdx.x & 63;
    int half = lane >> 5;
    int sub  = lane & 31;
    int node = wave * 2 + half;
    if (node >= N_NODES) return;

    float nn = nacc[node];
    float inv_n = 1.f / (nn == 0.f ? 1.f : nn);

    float4 xv = ((const float4*)(x + (size_t)node * HIDDEN))[sub];
    float4 y;
    {
        float h;
        h = xv.x * inv_n; h = h > 0.f ? h : 0.f; y.x = h + xv.x;
        h = xv.y * inv_n; h = h > 0.f ? h : 0.f; y.y = h + xv.y;
        h = xv.z * inv_n; h = h > 0.f ? h : 0.f; y.z = h + xv.z;
        h = xv.w * inv_n; h = h > 0.f ? h : 0.f; y.w = h + xv.w;
    }

    float ss = y.x * y.x + y.y * y.y + y.z * y.z + y.w * y.w;
    #pragma unroll
    for (int off = 16; off > 0; off >>= 1) ss += __shfl_xor(ss, off);
    float inv_rms = rsqrtf(ss * (1.f / HIDDEN) + EPS);

    float4 wv = ((const float4*)norm_w)[sub];
    float4 bv = ((const float4*)norm_b)[sub];
    float4 ov;
    ov.x = wv.x * (y.x * inv_rms) + bv.x;
    ov.y = wv.y * (y.y * inv_rms) + bv.y;
    ov.z = wv.z * (y.z * inv_rms) + bv.z;
    ov.w = wv.w * (y.w * inv_rms) + bv.w;
    ((float4*)(out + (size_t)node * HIDDEN))[sub] = ov;
}

extern "C" void kernel_launch(void* const* d_in, const int* in_sizes, int n_in,
                              void* d_out, int out_size, void* d_ws, size_t ws_size,
                              hipStream_t stream) {
    const float* x      = (const float*)d_in[0];
    const float* W      = (const float*)d_in[1];
    const float* b      = (const float*)d_in[2];
    const float* att_w  = (const float*)d_in[3];
    const float* norm_w = (const float*)d_in[4];
    const float* norm_b = (const float*)d_in[5];
    const int*   e      = (const int*)d_in[6];
    float* out = (float*)d_out;

    // workspace layout (floats): u[128] v[128] c[1] pad | p[N] q[N] nacc[N]
    float* ws = (float*)d_ws;
    float* u    = ws;
    float* v    = ws + 128;
    float* c    = ws + 256;
    float* p    = ws + 1024;
    float* q    = p + N_NODES;
    float* nacc = q + N_NODES;

    precompute_uvc<<<1, 512, 0, stream>>>(W, b, att_w, u, v, c);

    {   // 2 nodes/wave, 4 waves/block -> 8 nodes/block
        int blocks = (N_NODES + 7) / 8;
        node_dots<<<blocks, 256, 0, stream>>>(x, u, v, p, q, nacc);
    }
    {
        int blocks = (N_EDGES + 255) / 256;
        edge_kernel<<<blocks, 256, 0, stream>>>(e, p, q, c, nacc);
    }
    {
        int blocks = (N_NODES + 7) / 8;
        final_kernel<<<blocks, 256, 0, stream>>>(x, nacc, norm_w, norm_b, out);
    }
}